// Round 1
// baseline (489.157 us; speedup 1.0000x reference)
//
#include <hip/hip_runtime.h>

typedef _Float16 f16;
typedef _Float16 f16x4 __attribute__((ext_vector_type(4)));
typedef _Float16 f16x8 __attribute__((ext_vector_type(8)));
typedef float    f32x4 __attribute__((ext_vector_type(4)));

#define SEQ   1024
#define HID   512
#define NHEAD 8
#define DH    256
#define INTER 2048
#define BATCH 8
#define ROWS  (BATCH * SEQ)   // 8192

// async global->LDS, 16B per lane. LDS dest is wave-uniform base + lane*16.
__device__ __forceinline__ void g2l16(const void* g, void* l) {
  __builtin_amdgcn_global_load_lds(
      (const __attribute__((address_space(1))) void*)g,
      (__attribute__((address_space(3))) void*)l, 16, 0, 0);
}

// ---------------------------------------------------------------------------
// core: C(128x128) += A(128xK) * B^T(128xK), both operands k-fast row-major,
// ld == K. BK=32, global_load_lds DMA staging (m97 structure), LDS
// double-buffer, 1 barrier/slab. LDS layout: slot s (8-f16 chunks) holds
// row r=s>>2, octet-slot q=s&3 containing GLOBAL k-octet q ^ ((r>>1)&3)
// (involution applied on the pre-swizzled global source address; the
// ds_read_b128 side XORs the same -> conflict-free, data correct).
// 16x16x32 f16 MFMA, 4 waves x (4x4 tiles). C/D: col=lane&15, row=(lane>>4)*4+r.
// ---------------------------------------------------------------------------
__device__ __forceinline__ void mm_core(const f16* __restrict__ At,
                                        const f16* __restrict__ Bt,
                                        int K, f32x4 (&acc)[4][4]) {
  __shared__ __align__(16) f16 As[2 * 4096];
  __shared__ __align__(16) f16 Bs[2 * 4096];
  const int tid  = threadIdx.x;
  const int lane = tid & 63, wv = tid >> 6;
  const int wm = (wv >> 1) * 64, wn = (wv & 1) * 64;
  const int lrow  = lane & 15;
  const int kfrag = (lane >> 4) * 8;

  // staging geometry: slab = 128 rows x 32 k = 512 chunks of 16B.
  // wave wv stages chunks [wv*128, wv*128+128) via two 64-lane DMA calls.
  const int c0  = wv * 128 + lane;
  const int r0c = c0 >> 2, q0c = c0 & 3;
  const int c1  = c0 + 64;
  const int r1c = c1 >> 2, q1c = c1 & 3;
  const int ga0 = r0c * K + ((q0c ^ ((r0c >> 1) & 3)) << 3);  // pre-swizzled src
  const int ga1 = r1c * K + ((q1c ^ ((r1c >> 1) & 3)) << 3);
  f16* lA0 = &As[wv * 1024];        // chunk base wv*128 -> f16 offset wv*1024
  f16* lA1 = &As[wv * 1024 + 512];
  f16* lB0 = &Bs[wv * 1024];
  f16* lB1 = &Bs[wv * 1024 + 512];

  // swizzled fragment read offsets
  int aoff[4], boff[4];
  #pragma unroll
  for (int t = 0; t < 4; ++t) {
    int ra = wm + t * 16 + lrow;
    aoff[t] = ra * 32 + (kfrag ^ (((ra >> 1) & 3) << 3));
    int rb = wn + t * 16 + lrow;
    boff[t] = rb * 32 + (kfrag ^ (((rb >> 1) & 3) << 3));
  }

  // prologue: stage slab 0 -> buffer 0 (DMA), drain at barrier
  g2l16(At + ga0, lA0);
  g2l16(At + ga1, lA1);
  g2l16(Bt + ga0, lB0);
  g2l16(Bt + ga1, lB1);
  __syncthreads();

  int cur = 0;
  for (int k0 = 0; k0 < K; k0 += 32) {
    if (k0 + 32 < K) {   // issue next-slab DMA into other buffer; it drains
      const int nb = (cur ^ 1) * 4096;            // at this iter's barrier
      g2l16(At + (k0 + 32) + ga0, lA0 + nb);
      g2l16(At + (k0 + 32) + ga1, lA1 + nb);
      g2l16(Bt + (k0 + 32) + ga0, lB0 + nb);
      g2l16(Bt + (k0 + 32) + ga1, lB1 + nb);
    }
    const int cb = cur * 4096;
    f16x8 af[4], bf[4];
    #pragma unroll
    for (int t = 0; t < 4; ++t) {
      af[t] = *(const f16x8*)&As[cb + aoff[t]];
      bf[t] = *(const f16x8*)&Bs[cb + boff[t]];
    }
    #pragma unroll
    for (int i = 0; i < 4; ++i)
      #pragma unroll
      for (int j = 0; j < 4; ++j)
        acc[i][j] = __builtin_amdgcn_mfma_f32_16x16x32_f16(af[i], bf[j],
                                                           acc[i][j], 0, 0, 0);
    __syncthreads();   // drains vmcnt(0): next-slab DMA complete, reads done
    cur ^= 1;
  }
}

__device__ __forceinline__ void zero_acc(f32x4 (&acc)[4][4]) {
  f32x4 z = {0.f, 0.f, 0.f, 0.f};
  #pragma unroll
  for (int i = 0; i < 4; ++i)
    #pragma unroll
    for (int j = 0; j < 4; ++j) acc[i][j] = z;
}

// ---------------------------------------------------------------------------
// GEMM writing activation in per-head transposed layout Xt[b,h,d,s] (f16).
// A: [8192][K] f16, W: [2048][K] f16. N fixed = 2048 (8 heads x 256).
// ---------------------------------------------------------------------------
__global__ __launch_bounds__(256) void gemm_t_kernel(
    const f16* __restrict__ A, const f16* __restrict__ W,
    f16* __restrict__ Xt, int K) {
  int row0 = blockIdx.y * 128, col0 = blockIdx.x * 128;
  f32x4 acc[4][4];
  zero_acc(acc);
  mm_core(A + (size_t)row0 * K, W + (size_t)col0 * K, K, acc);
  int tid = threadIdx.x, lane = tid & 63, wv = tid >> 6;
  int wm = (wv >> 1) * 64, wn = (wv & 1) * 64;
  int cn = lane & 15, rbase = (lane >> 4) * 4;
  int b = row0 >> 10, sbase = row0 & 1023;
  #pragma unroll
  for (int mt = 0; mt < 4; ++mt) {
    int s = sbase + wm + mt * 16 + rbase;            // 4 consecutive s
    #pragma unroll
    for (int nt = 0; nt < 4; ++nt) {
      int n = col0 + wn + nt * 16 + cn;
      int h = n >> 8, d = n & 255;
      f16x4 v = {(f16)acc[mt][nt][0], (f16)acc[mt][nt][1],
                 (f16)acc[mt][nt][2], (f16)acc[mt][nt][3]};
      *(f16x4*)&Xt[(((size_t)(b * 8 + h) * 256 + d) << 10) + s] = v;
    }
  }
}

// ---------------------------------------------------------------------------
// per-head seq mix + bias + square:
// Y[(b,t),(h,d)] = ( sum_s Mt[h,t,s] * Xt[b,h,d,s] + bias[h,d] )^2   (f16 out)
// ---------------------------------------------------------------------------
__global__ __launch_bounds__(256) void mut_kernel(
    const f16* __restrict__ Mt, const f16* __restrict__ Xt,
    const float* __restrict__ bias, f16* __restrict__ Y) {
  int b = blockIdx.z >> 3, h = blockIdx.z & 7;
  int t0 = blockIdx.y * 128, d0 = blockIdx.x * 128;
  f32x4 acc[4][4];
  zero_acc(acc);
  const f16* Ap = Mt + ((size_t)h << 20) + ((size_t)t0 << 10);
  const f16* Bp = Xt + (((size_t)(b * 8 + h) * 256 + d0) << 10);
  mm_core(Ap, Bp, SEQ, acc);
  int tid = threadIdx.x, lane = tid & 63, wv = tid >> 6;
  int wm = (wv >> 1) * 64, wn = (wv & 1) * 64;
  int cn = lane & 15, rbase = (lane >> 4) * 4;
  #pragma unroll
  for (int mt = 0; mt < 4; ++mt) {
    int t = t0 + wm + mt * 16 + rbase;
    #pragma unroll
    for (int nt = 0; nt < 4; ++nt) {
      int d = d0 + wn + nt * 16 + cn;
      float bb = bias[(h << 8) + d];
      size_t base = (((size_t)(b << 10) + t) << 11) + (h << 8) + d;
      #pragma unroll
      for (int r = 0; r < 4; ++r) {
        float v = acc[mt][nt][r] + bb;
        Y[base + (size_t)r * INTER] = (f16)(v * v);
      }
    }
  }
}

// ---------------------------------------------------------------------------
// final GEMM: out fp32 = A @ W^T + bias.  A: [8192][K] f16, W: [N][K] f16.
// ---------------------------------------------------------------------------
__global__ __launch_bounds__(256) void gemm_out_kernel(
    const f16* __restrict__ A, const f16* __restrict__ W,
    const float* __restrict__ bias, float* __restrict__ out, int K, int N) {
  int row0 = blockIdx.y * 128, col0 = blockIdx.x * 128;
  f32x4 acc[4][4];
  zero_acc(acc);
  mm_core(A + (size_t)row0 * K, W + (size_t)col0 * K, K, acc);
  int tid = threadIdx.x, lane = tid & 63, wv = tid >> 6;
  int wm = (wv >> 1) * 64, wn = (wv & 1) * 64;
  int cn = lane & 15, rbase = (lane >> 4) * 4;
  #pragma unroll
  for (int mt = 0; mt < 4; ++mt) {
    int r0 = row0 + wm + mt * 16 + rbase;
    #pragma unroll
    for (int nt = 0; nt < 4; ++nt) {
      int col = col0 + wn + nt * 16 + cn;
      float bb = bias[col];
      #pragma unroll
      for (int r = 0; r < 4; ++r)
        out[(size_t)(r0 + r) * N + col] = acc[mt][nt][r] + bb;
    }
  }
}

// ---------------------------------------------------------------------------
// embeddings + layernorm -> f16
// ---------------------------------------------------------------------------
__global__ __launch_bounds__(256) void embed_ln_kernel(
    const int* __restrict__ x, const float* __restrict__ wemb,
    const float* __restrict__ pemb, const float* __restrict__ temb,
    const float* __restrict__ lnw, const float* __restrict__ lnb,
    f16* __restrict__ out) {
  int row = blockIdx.x;
  int s = row & (SEQ - 1);
  int tok = x[row];
  const float* we = wemb + (size_t)tok * HID;
  const float* pe = pemb + (size_t)s * HID;
  int c = threadIdx.x;
  float e0 = we[c] + pe[c] + temb[c];
  float e1 = we[c + 256] + pe[c + 256] + temb[c + 256];
  float s1 = e0 + e1, s2 = e0 * e0 + e1 * e1;
  #pragma unroll
  for (int off = 32; off > 0; off >>= 1) {
    s1 += __shfl_down(s1, off, 64);
    s2 += __shfl_down(s2, off, 64);
  }
  __shared__ float r1[4], r2[4];
  int wid = threadIdx.x >> 6, lane = threadIdx.x & 63;
  if (lane == 0) { r1[wid] = s1; r2[wid] = s2; }
  __syncthreads();
  float S1 = r1[0] + r1[1] + r1[2] + r1[3];
  float S2 = r2[0] + r2[1] + r2[2] + r2[3];
  float m = S1 * (1.0f / HID);
  float v = S2 * (1.0f / HID) - m * m;
  float inv = rsqrtf(v + 1e-12f);
  f16* o = out + (size_t)row * HID;
  o[c]       = (f16)((e0 - m) * inv * lnw[c]       + lnb[c]);
  o[c + 256] = (f16)((e1 - m) * inv * lnw[c + 256] + lnb[c + 256]);
}

// ---------------------------------------------------------------------------
// f32 -> f16 cast (n % 4 == 0)
// ---------------------------------------------------------------------------
__global__ __launch_bounds__(256) void cast_f16_kernel(
    const float* __restrict__ in, f16* __restrict__ out, int n) {
  int i = (blockIdx.x * 256 + threadIdx.x) * 4;
  if (i < n) {
    float4 v = *(const float4*)(in + i);
    f16x4 o = {(f16)v.x, (f16)v.y, (f16)v.z, (f16)v.w};
    *(f16x4*)(out + i) = o;
  }
}

// ---------------------------------------------------------------------------
// per-head transpose+cast: Mt[h][t][s] = (f16) M[h][s][t]   (1024x1024 x 8)
// ---------------------------------------------------------------------------
__global__ __launch_bounds__(256) void mtrans_kernel(
    const float* __restrict__ M, f16* __restrict__ Mt) {
  __shared__ float T[32][33];
  int h = blockIdx.z;
  int s0 = blockIdx.y * 32, t0 = blockIdx.x * 32;
  int tx = threadIdx.x & 31, ty = threadIdx.x >> 5;   // ty 0..7
  const float* Mh = M + ((size_t)h << 20);
  #pragma unroll
  for (int i = 0; i < 32; i += 8)
    T[ty + i][tx] = Mh[((size_t)(s0 + ty + i) << 10) + t0 + tx];
  __syncthreads();
  f16* Mth = Mt + ((size_t)h << 20);
  #pragma unroll
  for (int i = 0; i < 32; i += 8)
    Mth[((size_t)(t0 + ty + i) << 10) + s0 + tx] = (f16)T[tx][ty + i];
}

// ---------------------------------------------------------------------------
extern "C" void kernel_launch(void* const* d_in, const int* in_sizes, int n_in,
                              void* d_out, int out_size, void* d_ws, size_t ws_size,
                              hipStream_t stream) {
  const int*   x        = (const int*)d_in[0];
  const float* wemb     = (const float*)d_in[1];
  const float* pemb     = (const float*)d_in[2];
  const float* temb     = (const float*)d_in[3];
  const float* lnw      = (const float*)d_in[4];
  const float* lnb      = (const float*)d_in[5];
  const float* init_d   = (const float*)d_in[6];
  const float* init_b   = (const float*)d_in[7];
  const float* init_M   = (const float*)d_in[8];
  const float* inter0_d = (const float*)d_in[9];
  const float* inter0_b = (const float*)d_in[10];
  const float* inter0_M = (const float*)d_in[11];
  const float* final_d  = (const float*)d_in[12];
  const float* final_b  = (const float*)d_in[13];
  float* out = (float*)d_out;

  // aliased f16 workspace regions (bytes):
  char* ws = (char*)d_ws;
  f16* R0 = (f16*)(ws);                 //  8.4MB: X0 (8192x512)  then W2f (2048x2048)
  f16* R1 = (f16*)(ws + 8388608);       //  2.1MB: W1f (2048x512) then W3f (512x2048)
  f16* R2 = (f16*)(ws + 10485760);      // 16.8MB: Mt1 then Mt2   (8x1024x1024)
  f16* R3 = (f16*)(ws + 27262976);      // 33.6MB: Xt1 then bufD  (8192x2048)
  f16* R4 = (f16*)(ws + 60817408);      // 33.6MB: bufB
  f16* R5 = (f16*)(ws + 94371840);      // 33.6MB: Xt2

  // 1. embeddings + LN -> X0 (f16)
  embed_ln_kernel<<<ROWS, 256, 0, stream>>>(x, wemb, pemb, temb, lnw, lnb, R0);
  // 2. W1 -> f16 ; Mt1
  cast_f16_kernel<<<(INTER * HID / 4 + 255) / 256, 256, 0, stream>>>(init_d, R1, INTER * HID);
  mtrans_kernel<<<dim3(32, 32, 8), 256, 0, stream>>>(init_M, R2);
  // 3. gemm1: Xt1 = X0 @ W1^T  (transposed-per-head epilogue)
  gemm_t_kernel<<<dim3(INTER / 128, ROWS / 128), 256, 0, stream>>>(R0, R1, R3, HID);
  // 4. mut1 -> bufB
  mut_kernel<<<dim3(DH / 128, SEQ / 128, BATCH * NHEAD), 256, 0, stream>>>(R2, R3, init_b, R4);
  // 5. W2 -> f16 (over X0) ; Mt2 (over Mt1)
  cast_f16_kernel<<<(INTER * INTER / 4 + 255) / 256, 256, 0, stream>>>(inter0_d, R0, INTER * INTER);
  mtrans_kernel<<<dim3(32, 32, 8), 256, 0, stream>>>(inter0_M, R2);
  // 6. gemm2: Xt2 = bufB @ W2^T
  gemm_t_kernel<<<dim3(INTER / 128, ROWS / 128), 256, 0, stream>>>(R4, R0, R5, INTER);
  // 7. mut2 -> bufD (over Xt1)
  mut_kernel<<<dim3(DH / 128, SEQ / 128, BATCH * NHEAD), 256, 0, stream>>>(R2, R5, inter0_b, R3);
  // 8. W3 -> f16 (over W1f)
  cast_f16_kernel<<<(HID * INTER / 4 + 255) / 256, 256, 0, stream>>>(final_d, R1, HID * INTER);
  // 9. gemm3: out = bufD @ W3^T + bias (fp32 out)
  gemm_out_kernel<<<dim3(HID / 128, ROWS / 128), 256, 0, stream>>>(R3, R1, final_b, out, INTER, HID);
}

// Round 3
// 425.382 us; speedup vs baseline: 1.1499x; 1.1499x over previous
//
#include <hip/hip_runtime.h>

typedef _Float16 f16;
typedef _Float16 f16x4 __attribute__((ext_vector_type(4)));
typedef _Float16 f16x8 __attribute__((ext_vector_type(8)));
typedef float    f32x4 __attribute__((ext_vector_type(4)));

#define SEQ   1024
#define HID   512
#define NHEAD 8
#define DH    256
#define INTER 2048
#define BATCH 8
#define ROWS  (BATCH * SEQ)   // 8192

// async global->LDS, 16B per lane. LDS dest is wave-uniform base + lane*16.
__device__ __forceinline__ void g2l16(const void* g, void* l) {
  __builtin_amdgcn_global_load_lds(
      (const __attribute__((address_space(1))) void*)g,
      (__attribute__((address_space(3))) void*)l, 16, 0, 0);
}

// ===========================================================================
// 256x256 deep-pipelined core (counted-vmcnt, 3-slot LDS ring), BK=32.
// C(256x256) += A(256xK) * B^T(256xK); operands k-fast row-major, ld == K.
// 512 threads = 8 waves (2M x 4N); per-wave output 128x64 = acc[8][4].
// LDS: 3 ring slots x (A 16KiB + B 16KiB) = 96 KiB. Tile t reads slot t%3;
// staging for tile t+2 is issued DURING tile t into slot (t+2)%3 (disjoint
// from slots t%3 and (t+1)%3 -> race-free). Boundary: s_waitcnt vmcnt(4)
// (tile t+1 landed, tile t+2's 4 calls still in flight) + raw s_barrier.
// Swizzle: k-octet q of row r stored at slot q ^ ((r>>1)&3) (same involution
// as the verified 128-core: 8 consecutive rows cover all 32 banks -> 2-way
// aliasing = free; applied on pre-swizzled GLOBAL source, ds_read matches).
// Two 16-MFMA clusters per tile, staging interleaved; s_setprio around MFMA.
// ===========================================================================
__device__ __forceinline__ void mm_core256(const f16* __restrict__ At,
                                           const f16* __restrict__ Bt,
                                           int K, f32x4 (&acc)[8][4]) {
  __shared__ __align__(16) f16 As[3 * 8192];
  __shared__ __align__(16) f16 Bs[3 * 8192];
  const int tid  = threadIdx.x;
  const int lane = tid & 63, wv = tid >> 6;
  const int wrow = (wv >> 2) * 128, wcol = (wv & 3) * 64;

  // staging: tile = 256 rows x 4 k-octets = 1024 chunks of 16B; 2 calls of
  // 512 lanes. call j covers chunk j*512+tid: r=chunk>>2, s=chunk&3,
  // global octet q = s ^ ((r>>1)&3). LDS layout linear: f16 off = chunk*8.
  const int ch0 = tid, ch1 = tid + 512;
  const int r0 = ch0 >> 2, s0 = ch0 & 3;
  const int r1 = ch1 >> 2, s1 = ch1 & 3;
  const int g0 = r0 * K + ((s0 ^ ((r0 >> 1) & 3)) << 3);  // pre-swizzled src
  const int g1 = r1 * K + ((s1 ^ ((r1 >> 1) & 3)) << 3);
  const int l0 = wv * 512;          // per-wave LDS base (f16), call 0
  const int l1 = 4096 + wv * 512;   // call 1

  // fragment read offsets (swizzled, matches source permutation)
  int aoff[8], boff[4];
  const int q = lane >> 4;
  #pragma unroll
  for (int m = 0; m < 8; ++m) {
    int r = wrow + m * 16 + (lane & 15);
    aoff[m] = r * 32 + ((q ^ ((r >> 1) & 3)) << 3);
  }
  #pragma unroll
  for (int n = 0; n < 4; ++n) {
    int r = wcol + n * 16 + (lane & 15);
    boff[n] = r * 32 + ((q ^ ((r >> 1) & 3)) << 3);
  }

  const int nt = K >> 5;
  // prologue: stage tile 0 -> slot 0, tile 1 -> slot 1 (8 calls)
  g2l16(At + g0, &As[l0]);
  g2l16(At + g1, &As[l1]);
  g2l16(Bt + g0, &Bs[l0]);
  g2l16(Bt + g1, &Bs[l1]);
  g2l16(At + 32 + g0, &As[8192 + l0]);
  g2l16(At + 32 + g1, &As[8192 + l1]);
  g2l16(Bt + 32 + g0, &Bs[8192 + l0]);
  g2l16(Bt + 32 + g1, &Bs[8192 + l1]);
  __builtin_amdgcn_sched_barrier(0);
  asm volatile("s_waitcnt vmcnt(4)" ::: "memory");   // tile 0 landed
  __builtin_amdgcn_s_barrier();
  __builtin_amdgcn_sched_barrier(0);

  int slot = 0;
  for (int t = 0; t < nt; ++t) {
    const int cb = slot * 8192;
    const int sb = (slot == 0 ? 2 : slot - 1) * 8192;  // slot (t+2)%3
    const bool pf = (t + 2 < nt);
    const int kpre = (t + 2) << 5;

    f16x8 bfr[4], af0[4], af1[4];
    #pragma unroll
    for (int n = 0; n < 4; ++n) bfr[n] = *(const f16x8*)&Bs[cb + boff[n]];
    #pragma unroll
    for (int m = 0; m < 4; ++m) af0[m] = *(const f16x8*)&As[cb + aoff[m]];
    if (pf) {                       // stage A of tile t+2
      g2l16(At + kpre + g0, &As[sb + l0]);
      g2l16(At + kpre + g1, &As[sb + l1]);
    }
    __builtin_amdgcn_s_setprio(1);
    #pragma unroll
    for (int m = 0; m < 4; ++m)
      #pragma unroll
      for (int n = 0; n < 4; ++n)
        acc[m][n] = __builtin_amdgcn_mfma_f32_16x16x32_f16(af0[m], bfr[n],
                                                           acc[m][n], 0, 0, 0);
    __builtin_amdgcn_s_setprio(0);
    #pragma unroll
    for (int m = 0; m < 4; ++m) af1[m] = *(const f16x8*)&As[cb + aoff[m + 4]];
    if (pf) {                       // stage B of tile t+2
      g2l16(Bt + kpre + g0, &Bs[sb + l0]);
      g2l16(Bt + kpre + g1, &Bs[sb + l1]);
    }
    __builtin_amdgcn_s_setprio(1);
    #pragma unroll
    for (int m = 0; m < 4; ++m)
      #pragma unroll
      for (int n = 0; n < 4; ++n)
        acc[m + 4][n] = __builtin_amdgcn_mfma_f32_16x16x32_f16(af1[m], bfr[n],
                                                               acc[m + 4][n], 0, 0, 0);
    __builtin_amdgcn_s_setprio(0);
    if (t + 1 < nt) {
      __builtin_amdgcn_sched_barrier(0);
      if (pf) asm volatile("s_waitcnt vmcnt(4)" ::: "memory");  // t+1 landed
      else    asm volatile("s_waitcnt vmcnt(0)" ::: "memory");  // drain tail
      __builtin_amdgcn_s_barrier();
      __builtin_amdgcn_sched_barrier(0);
    }
    slot = (slot == 2) ? 0 : slot + 1;
  }
}

__device__ __forceinline__ void zero_acc8(f32x4 (&acc)[8][4]) {
  f32x4 z = {0.f, 0.f, 0.f, 0.f};
  #pragma unroll
  for (int i = 0; i < 8; ++i)
    #pragma unroll
    for (int j = 0; j < 4; ++j) acc[i][j] = z;
}

// ---------------------------------------------------------------------------
// 256-tile GEMM writing activation in per-head transposed layout Xt[b,h,d,s].
// A: [8192][K] f16, W: [2048][K] f16. N fixed = 2048 (8 heads x 256).
// ---------------------------------------------------------------------------
__global__ __launch_bounds__(512, 2) void gemm256_t_kernel(
    const f16* __restrict__ A, const f16* __restrict__ W,
    f16* __restrict__ Xt, int K) {
  int row0 = blockIdx.y * 256, col0 = blockIdx.x * 256;
  f32x4 acc[8][4];
  zero_acc8(acc);
  mm_core256(A + (size_t)row0 * K, W + (size_t)col0 * K, K, acc);
  int tid = threadIdx.x, lane = tid & 63, wv = tid >> 6;
  int wrow = (wv >> 2) * 128, wcol = (wv & 3) * 64;
  int cn = lane & 15, rbase = (lane >> 4) * 4;
  int b = row0 >> 10, sbase = row0 & 1023;
  #pragma unroll
  for (int m = 0; m < 8; ++m) {
    int s = sbase + wrow + m * 16 + rbase;           // 4 consecutive s
    #pragma unroll
    for (int n = 0; n < 4; ++n) {
      int col = col0 + wcol + n * 16 + cn;
      int h = col >> 8, d = col & 255;
      f16x4 v = {(f16)acc[m][n][0], (f16)acc[m][n][1],
                 (f16)acc[m][n][2], (f16)acc[m][n][3]};
      *(f16x4*)&Xt[(((size_t)(b * 8 + h) * 256 + d) << 10) + s] = v;
    }
  }
}

// ---------------------------------------------------------------------------
// 256-tile per-head seq mix + bias + square:
// Y[(b,t),(h,d)] = ( sum_s Mt[h,t,s] * Xt[b,h,d,s] + bias[h,d] )^2 (f16 out)
// grid: (1, SEQ/256, B*H). N-tile covers the full 256-d head.
// ---------------------------------------------------------------------------
__global__ __launch_bounds__(512, 2) void mut256_kernel(
    const f16* __restrict__ Mt, const f16* __restrict__ Xt,
    const float* __restrict__ bias, f16* __restrict__ Y) {
  int b = blockIdx.z >> 3, h = blockIdx.z & 7;
  int t0 = blockIdx.y * 256;
  f32x4 acc[8][4];
  zero_acc8(acc);
  const f16* Ap = Mt + ((size_t)h << 20) + ((size_t)t0 << 10);
  const f16* Bp = Xt + (((size_t)(b * 8 + h)) << 18);
  mm_core256(Ap, Bp, SEQ, acc);
  int tid = threadIdx.x, lane = tid & 63, wv = tid >> 6;
  int wrow = (wv >> 2) * 128, wcol = (wv & 3) * 64;
  int cn = lane & 15, rbase = (lane >> 4) * 4;
  #pragma unroll
  for (int m = 0; m < 8; ++m) {
    int t = t0 + wrow + m * 16 + rbase;
    #pragma unroll
    for (int n = 0; n < 4; ++n) {
      int d = wcol + n * 16 + cn;
      float bb = bias[(h << 8) + d];
      size_t base = (((size_t)(b << 10) + t) << 11) + (h << 8) + d;
      #pragma unroll
      for (int r = 0; r < 4; ++r) {
        float v = acc[m][n][r] + bb;
        Y[base + (size_t)r * INTER] = (f16)(v * v);
      }
    }
  }
}

// ===========================================================================
// 128x128 core (verified): BK=32, global_load_lds staging, double buffer.
// Kept for gemm3 (N=512 -> 256-tile grid would underfill the GPU).
// ===========================================================================
__device__ __forceinline__ void mm_core(const f16* __restrict__ At,
                                        const f16* __restrict__ Bt,
                                        int K, f32x4 (&acc)[4][4]) {
  __shared__ __align__(16) f16 As[2 * 4096];
  __shared__ __align__(16) f16 Bs[2 * 4096];
  const int tid  = threadIdx.x;
  const int lane = tid & 63, wv = tid >> 6;
  const int wm = (wv >> 1) * 64, wn = (wv & 1) * 64;
  const int lrow  = lane & 15;
  const int kfrag = (lane >> 4) * 8;
  const int c0  = wv * 128 + lane;
  const int r0c = c0 >> 2, q0c = c0 & 3;
  const int c1  = c0 + 64;
  const int r1c = c1 >> 2, q1c = c1 & 3;
  const int ga0 = r0c * K + ((q0c ^ ((r0c >> 1) & 3)) << 3);
  const int ga1 = r1c * K + ((q1c ^ ((r1c >> 1) & 3)) << 3);
  f16* lA0 = &As[wv * 1024];
  f16* lA1 = &As[wv * 1024 + 512];
  f16* lB0 = &Bs[wv * 1024];
  f16* lB1 = &Bs[wv * 1024 + 512];
  int aoff[4], boff[4];
  #pragma unroll
  for (int t = 0; t < 4; ++t) {
    int ra = wm + t * 16 + lrow;
    aoff[t] = ra * 32 + (kfrag ^ (((ra >> 1) & 3) << 3));
    int rb = wn + t * 16 + lrow;
    boff[t] = rb * 32 + (kfrag ^ (((rb >> 1) & 3) << 3));
  }
  g2l16(At + ga0, lA0);
  g2l16(At + ga1, lA1);
  g2l16(Bt + ga0, lB0);
  g2l16(Bt + ga1, lB1);
  __syncthreads();
  int cur = 0;
  for (int k0 = 0; k0 < K; k0 += 32) {
    if (k0 + 32 < K) {
      const int nb = (cur ^ 1) * 4096;
      g2l16(At + (k0 + 32) + ga0, lA0 + nb);
      g2l16(At + (k0 + 32) + ga1, lA1 + nb);
      g2l16(Bt + (k0 + 32) + ga0, lB0 + nb);
      g2l16(Bt + (k0 + 32) + ga1, lB1 + nb);
    }
    const int cb = cur * 4096;
    f16x8 af[4], bf[4];
    #pragma unroll
    for (int t = 0; t < 4; ++t) {
      af[t] = *(const f16x8*)&As[cb + aoff[t]];
      bf[t] = *(const f16x8*)&Bs[cb + boff[t]];
    }
    #pragma unroll
    for (int i = 0; i < 4; ++i)
      #pragma unroll
      for (int j = 0; j < 4; ++j)
        acc[i][j] = __builtin_amdgcn_mfma_f32_16x16x32_f16(af[i], bf[j],
                                                           acc[i][j], 0, 0, 0);
    __syncthreads();
    cur ^= 1;
  }
}

__device__ __forceinline__ void zero_acc(f32x4 (&acc)[4][4]) {
  f32x4 z = {0.f, 0.f, 0.f, 0.f};
  #pragma unroll
  for (int i = 0; i < 4; ++i)
    #pragma unroll
    for (int j = 0; j < 4; ++j) acc[i][j] = z;
}

// ---------------------------------------------------------------------------
// final GEMM: out fp32 = A @ W^T + bias.  A: [8192][K] f16, W: [N][K] f16.
// ---------------------------------------------------------------------------
__global__ __launch_bounds__(256) void gemm_out_kernel(
    const f16* __restrict__ A, const f16* __restrict__ W,
    const float* __restrict__ bias, float* __restrict__ out, int K, int N) {
  int row0 = blockIdx.y * 128, col0 = blockIdx.x * 128;
  f32x4 acc[4][4];
  zero_acc(acc);
  mm_core(A + (size_t)row0 * K, W + (size_t)col0 * K, K, acc);
  int tid = threadIdx.x, lane = tid & 63, wv = tid >> 6;
  int wm = (wv >> 1) * 64, wn = (wv & 1) * 64;
  int cn = lane & 15, rbase = (lane >> 4) * 4;
  #pragma unroll
  for (int mt = 0; mt < 4; ++mt) {
    int r0 = row0 + wm + mt * 16 + rbase;
    #pragma unroll
    for (int nt = 0; nt < 4; ++nt) {
      int col = col0 + wn + nt * 16 + cn;
      float bb = bias[col];
      #pragma unroll
      for (int r = 0; r < 4; ++r)
        out[(size_t)(r0 + r) * N + col] = acc[mt][nt][r] + bb;
    }
  }
}

// ---------------------------------------------------------------------------
// embeddings + layernorm -> f16
// ---------------------------------------------------------------------------
__global__ __launch_bounds__(256) void embed_ln_kernel(
    const int* __restrict__ x, const float* __restrict__ wemb,
    const float* __restrict__ pemb, const float* __restrict__ temb,
    const float* __restrict__ lnw, const float* __restrict__ lnb,
    f16* __restrict__ out) {
  int row = blockIdx.x;
  int s = row & (SEQ - 1);
  int tok = x[row];
  const float* we = wemb + (size_t)tok * HID;
  const float* pe = pemb + (size_t)s * HID;
  int c = threadIdx.x;
  float e0 = we[c] + pe[c] + temb[c];
  float e1 = we[c + 256] + pe[c + 256] + temb[c + 256];
  float s1 = e0 + e1, s2 = e0 * e0 + e1 * e1;
  #pragma unroll
  for (int off = 32; off > 0; off >>= 1) {
    s1 += __shfl_down(s1, off, 64);
    s2 += __shfl_down(s2, off, 64);
  }
  __shared__ float r1[4], r2[4];
  int wid = threadIdx.x >> 6, lane = threadIdx.x & 63;
  if (lane == 0) { r1[wid] = s1; r2[wid] = s2; }
  __syncthreads();
  float S1 = r1[0] + r1[1] + r1[2] + r1[3];
  float S2 = r2[0] + r2[1] + r2[2] + r2[3];
  float m = S1 * (1.0f / HID);
  float v = S2 * (1.0f / HID) - m * m;
  float inv = rsqrtf(v + 1e-12f);
  f16* o = out + (size_t)row * HID;
  o[c]       = (f16)((e0 - m) * inv * lnw[c]       + lnb[c]);
  o[c + 256] = (f16)((e1 - m) * inv * lnw[c + 256] + lnb[c + 256]);
}

// ---------------------------------------------------------------------------
// f32 -> f16 cast (n % 4 == 0)
// ---------------------------------------------------------------------------
__global__ __launch_bounds__(256) void cast_f16_kernel(
    const float* __restrict__ in, f16* __restrict__ out, int n) {
  int i = (blockIdx.x * 256 + threadIdx.x) * 4;
  if (i < n) {
    float4 v = *(const float4*)(in + i);
    f16x4 o = {(f16)v.x, (f16)v.y, (f16)v.z, (f16)v.w};
    *(f16x4*)(out + i) = o;
  }
}

// ---------------------------------------------------------------------------
// per-head transpose+cast: Mt[h][t][s] = (f16) M[h][s][t]   (1024x1024 x 8)
// ---------------------------------------------------------------------------
__global__ __launch_bounds__(256) void mtrans_kernel(
    const float* __restrict__ M, f16* __restrict__ Mt) {
  __shared__ float T[32][33];
  int h = blockIdx.z;
  int s0 = blockIdx.y * 32, t0 = blockIdx.x * 32;
  int tx = threadIdx.x & 31, ty = threadIdx.x >> 5;   // ty 0..7
  const float* Mh = M + ((size_t)h << 20);
  #pragma unroll
  for (int i = 0; i < 32; i += 8)
    T[ty + i][tx] = Mh[((size_t)(s0 + ty + i) << 10) + t0 + tx];
  __syncthreads();
  f16* Mth = Mt + ((size_t)h << 20);
  #pragma unroll
  for (int i = 0; i < 32; i += 8)
    Mth[((size_t)(t0 + ty + i) << 10) + s0 + tx] = (f16)T[tx][ty + i];
}

// ---------------------------------------------------------------------------
extern "C" void kernel_launch(void* const* d_in, const int* in_sizes, int n_in,
                              void* d_out, int out_size, void* d_ws, size_t ws_size,
                              hipStream_t stream) {
  const int*   x        = (const int*)d_in[0];
  const float* wemb     = (const float*)d_in[1];
  const float* pemb     = (const float*)d_in[2];
  const float* temb     = (const float*)d_in[3];
  const float* lnw      = (const float*)d_in[4];
  const float* lnb      = (const float*)d_in[5];
  const float* init_d   = (const float*)d_in[6];
  const float* init_b   = (const float*)d_in[7];
  const float* init_M   = (const float*)d_in[8];
  const float* inter0_d = (const float*)d_in[9];
  const float* inter0_b = (const float*)d_in[10];
  const float* inter0_M = (const float*)d_in[11];
  const float* final_d  = (const float*)d_in[12];
  const float* final_b  = (const float*)d_in[13];
  float* out = (float*)d_out;

  // aliased f16 workspace regions (bytes):
  char* ws = (char*)d_ws;
  f16* R0 = (f16*)(ws);                 //  8.4MB: X0 (8192x512)  then W2f (2048x2048)
  f16* R1 = (f16*)(ws + 8388608);       //  2.1MB: W1f (2048x512) then W3f (512x2048)
  f16* R2 = (f16*)(ws + 10485760);      // 16.8MB: Mt1 then Mt2   (8x1024x1024)
  f16* R3 = (f16*)(ws + 27262976);      // 33.6MB: Xt1 then bufD  (8192x2048)
  f16* R4 = (f16*)(ws + 60817408);      // 33.6MB: bufB
  f16* R5 = (f16*)(ws + 94371840);      // 33.6MB: Xt2

  // 1. embeddings + LN -> X0 (f16)
  embed_ln_kernel<<<ROWS, 256, 0, stream>>>(x, wemb, pemb, temb, lnw, lnb, R0);
  // 2. W1 -> f16 ; Mt1
  cast_f16_kernel<<<(INTER * HID / 4 + 255) / 256, 256, 0, stream>>>(init_d, R1, INTER * HID);
  mtrans_kernel<<<dim3(32, 32, 8), 256, 0, stream>>>(init_M, R2);
  // 3. gemm1: Xt1 = X0 @ W1^T  (transposed-per-head epilogue)
  gemm256_t_kernel<<<dim3(INTER / 256, ROWS / 256), 512, 0, stream>>>(R0, R1, R3, HID);
  // 4. mut1 -> bufB
  mut256_kernel<<<dim3(1, SEQ / 256, BATCH * NHEAD), 512, 0, stream>>>(R2, R3, init_b, R4);
  // 5. W2 -> f16 (over X0) ; Mt2 (over Mt1)
  cast_f16_kernel<<<(INTER * INTER / 4 + 255) / 256, 256, 0, stream>>>(inter0_d, R0, INTER * INTER);
  mtrans_kernel<<<dim3(32, 32, 8), 256, 0, stream>>>(inter0_M, R2);
  // 6. gemm2: Xt2 = bufB @ W2^T
  gemm256_t_kernel<<<dim3(INTER / 256, ROWS / 256), 512, 0, stream>>>(R4, R0, R5, INTER);
  // 7. mut2 -> bufD (over Xt1)
  mut256_kernel<<<dim3(1, SEQ / 256, BATCH * NHEAD), 512, 0, stream>>>(R2, R5, inter0_b, R3);
  // 8. W3 -> f16 (over W1f)
  cast_f16_kernel<<<(HID * INTER / 4 + 255) / 256, 256, 0, stream>>>(final_d, R1, HID * INTER);
  // 9. gemm3: out = bufD @ W3^T + bias (fp32 out)
  gemm_out_kernel<<<dim3(HID / 128, ROWS / 128), 256, 0, stream>>>(R3, R1, final_b, out, INTER, HID);
}

// Round 4
// 423.640 us; speedup vs baseline: 1.1547x; 1.0041x over previous
//
#include <hip/hip_runtime.h>

typedef _Float16 f16;
typedef _Float16 f16x4 __attribute__((ext_vector_type(4)));
typedef _Float16 f16x8 __attribute__((ext_vector_type(8)));
typedef float    f32x4 __attribute__((ext_vector_type(4)));

#define SEQ   1024
#define HID   512
#define NHEAD 8
#define DH    256
#define INTER 2048
#define BATCH 8
#define ROWS  (BATCH * SEQ)   // 8192

// async global->LDS, 16B per lane. LDS dest is wave-uniform base + lane*16.
__device__ __forceinline__ void g2l16(const void* g, void* l) {
  __builtin_amdgcn_global_load_lds(
      (const __attribute__((address_space(1))) void*)g,
      (__attribute__((address_space(3))) void*)l, 16, 0, 0);
}

#define SYNC_VM4() do { __builtin_amdgcn_sched_barrier(0);            \
    asm volatile("s_waitcnt vmcnt(4)" ::: "memory");                  \
    __builtin_amdgcn_s_barrier(); __builtin_amdgcn_sched_barrier(0); } while (0)
#define SYNC_VM0() do { __builtin_amdgcn_sched_barrier(0);            \
    asm volatile("s_waitcnt vmcnt(0)" ::: "memory");                  \
    __builtin_amdgcn_s_barrier(); __builtin_amdgcn_sched_barrier(0); } while (0)

// ===========================================================================
// 256x256 8-phase core (m201-style schedule), BK=64 = 2 x K-32 subtiles.
// C(256x256) += A(256xK) * B^T(256xK); operands k-fast row-major, ld == K.
// 512 threads = 8 waves (2M x 4N); per-wave output 128x64 = acc[8][4].
// LDS: 2 buffers x (A 32KiB + B 32KiB) = 128 KiB -> 1 block/CU.
// Each subtile keeps the verified 0-conflict layout: k-octet q of row r at
// slot q ^ ((r>>1)&3) (involution pre-applied on the GLOBAL source address;
// ds_read applies the same).
// Per slab t: 4 phases, each {ds_read subtile-frags; issue 2 g2l for slab
// t+1; s_barrier; setprio(1); 16 MFMA; setprio(0); s_barrier}. Counted
// waits (vmcnt(4)) at mid-slab and slab boundary only: per-wave issue order
// A0,B0,A1,B1 makes the oldest-4 exactly the subtiles the next phases read,
// with 4 loads always in flight across barriers (T3+T4). Last slab:
// mid-wait drains (vmcnt(0)), uniform branch.
// ===========================================================================
__device__ __forceinline__ void mm_core256(const f16* __restrict__ At,
                                           const f16* __restrict__ Bt,
                                           int K, f32x4 (&acc)[8][4]) {
  __shared__ __align__(16) f16 As[2 * 16384];
  __shared__ __align__(16) f16 Bs[2 * 16384];
  const int tid  = threadIdx.x;
  const int lane = tid & 63, wv = tid >> 6;
  const int wrow = (wv >> 2) * 128, wcol = (wv & 3) * 64;

  // staging: subtile = 256 rows x 4 k-octets = 1024 chunks of 16B; 2 calls.
  // call j covers chunk j*512+tid: r=c>>2, s=c&3, global octet q=s^((r>>1)&3).
  const int c0 = tid, c1 = tid + 512;
  const int r0 = c0 >> 2, s0 = c0 & 3;
  const int r1 = c1 >> 2, s1 = c1 & 3;
  const int g0 = r0 * K + ((s0 ^ ((r0 >> 1) & 3)) << 3);  // pre-swizzled src
  const int g1 = r1 * K + ((s1 ^ ((r1 >> 1) & 3)) << 3);
  const int l0 = wv * 512;          // per-wave LDS base (f16), call 0
  const int l1 = 4096 + wv * 512;   // call 1

  // fragment read offsets within a subtile (swizzled, matches source perm)
  int aoff[8], boff[4];
  const int q = lane >> 4;
  #pragma unroll
  for (int m = 0; m < 8; ++m) {
    int r = wrow + m * 16 + (lane & 15);
    aoff[m] = r * 32 + ((q ^ ((r >> 1) & 3)) << 3);
  }
  #pragma unroll
  for (int n = 0; n < 4; ++n) {
    int r = wcol + n * 16 + (lane & 15);
    boff[n] = r * 32 + ((q ^ ((r >> 1) & 3)) << 3);
  }

  const int nt = K >> 6;   // BK=64 slabs
  // prologue: slab 0 -> buffer 0; order A(0,0),B(0,0),A(0,1),B(0,1)
  g2l16(At + g0, &As[l0]);
  g2l16(At + g1, &As[l1]);
  g2l16(Bt + g0, &Bs[l0]);
  g2l16(Bt + g1, &Bs[l1]);
  g2l16(At + 32 + g0, &As[8192 + l0]);
  g2l16(At + 32 + g1, &As[8192 + l1]);
  g2l16(Bt + 32 + g0, &Bs[8192 + l0]);
  g2l16(Bt + 32 + g1, &Bs[8192 + l1]);
  SYNC_VM4();   // A(0,0),B(0,0) landed; A(0,1),B(0,1) in flight

  for (int t = 0; t < nt; ++t) {
    const int cb = (t & 1) * 16384;         // current buffer
    const int nb = ((t + 1) & 1) * 16384;   // next buffer
    const bool pf = (t + 1 < nt);
    const int kn = (t + 1) << 6;

    // ---- P1: k-sub 0, m 0-3 (reads B(t,0) + A(t,0) lower) ----
    f16x8 b0[4], a0[4];
    #pragma unroll
    for (int n = 0; n < 4; ++n) b0[n] = *(const f16x8*)&Bs[cb + boff[n]];
    #pragma unroll
    for (int m = 0; m < 4; ++m) a0[m] = *(const f16x8*)&As[cb + aoff[m]];
    if (pf) {                     // issue A(t+1,0)
      g2l16(At + kn + g0, &As[nb + l0]);
      g2l16(At + kn + g1, &As[nb + l1]);
    }
    __builtin_amdgcn_s_barrier();
    __builtin_amdgcn_s_setprio(1);
    #pragma unroll
    for (int m = 0; m < 4; ++m)
      #pragma unroll
      for (int n = 0; n < 4; ++n)
        acc[m][n] = __builtin_amdgcn_mfma_f32_16x16x32_f16(a0[m], b0[n],
                                                           acc[m][n], 0, 0, 0);
    __builtin_amdgcn_s_setprio(0);
    __builtin_amdgcn_s_barrier();

    // ---- P2: k-sub 0, m 4-7 ----
    f16x8 a1[4];
    #pragma unroll
    for (int m = 0; m < 4; ++m) a1[m] = *(const f16x8*)&As[cb + aoff[m + 4]];
    if (pf) {                     // issue B(t+1,0)
      g2l16(Bt + kn + g0, &Bs[nb + l0]);
      g2l16(Bt + kn + g1, &Bs[nb + l1]);
    }
    __builtin_amdgcn_s_barrier();
    __builtin_amdgcn_s_setprio(1);
    #pragma unroll
    for (int m = 0; m < 4; ++m)
      #pragma unroll
      for (int n = 0; n < 4; ++n)
        acc[m + 4][n] = __builtin_amdgcn_mfma_f32_16x16x32_f16(a1[m], b0[n],
                                                               acc[m + 4][n], 0, 0, 0);
    __builtin_amdgcn_s_setprio(0);
    // mid sync: A(t,1),B(t,1) landed; A(t+1,0),B(t+1,0) stay in flight
    if (pf) SYNC_VM4(); else SYNC_VM0();

    // ---- P3: k-sub 1, m 0-3 (reads B(t,1) + A(t,1) lower) ----
    f16x8 b1[4], a2[4];
    #pragma unroll
    for (int n = 0; n < 4; ++n) b1[n] = *(const f16x8*)&Bs[cb + 8192 + boff[n]];
    #pragma unroll
    for (int m = 0; m < 4; ++m) a2[m] = *(const f16x8*)&As[cb + 8192 + aoff[m]];
    if (pf) {                     // issue A(t+1,1)
      g2l16(At + kn + 32 + g0, &As[nb + 8192 + l0]);
      g2l16(At + kn + 32 + g1, &As[nb + 8192 + l1]);
    }
    __builtin_amdgcn_s_barrier();
    __builtin_amdgcn_s_setprio(1);
    #pragma unroll
    for (int m = 0; m < 4; ++m)
      #pragma unroll
      for (int n = 0; n < 4; ++n)
        acc[m][n] = __builtin_amdgcn_mfma_f32_16x16x32_f16(a2[m], b1[n],
                                                           acc[m][n], 0, 0, 0);
    __builtin_amdgcn_s_setprio(0);
    __builtin_amdgcn_s_barrier();

    // ---- P4: k-sub 1, m 4-7 ----
    f16x8 a3[4];
    #pragma unroll
    for (int m = 0; m < 4; ++m) a3[m] = *(const f16x8*)&As[cb + 8192 + aoff[m + 4]];
    if (pf) {                     // issue B(t+1,1)
      g2l16(Bt + kn + 32 + g0, &Bs[nb + 8192 + l0]);
      g2l16(Bt + kn + 32 + g1, &Bs[nb + 8192 + l1]);
    }
    __builtin_amdgcn_s_barrier();
    __builtin_amdgcn_s_setprio(1);
    #pragma unroll
    for (int m = 0; m < 4; ++m)
      #pragma unroll
      for (int n = 0; n < 4; ++n)
        acc[m + 4][n] = __builtin_amdgcn_mfma_f32_16x16x32_f16(a3[m], b1[n],
                                                               acc[m + 4][n], 0, 0, 0);
    __builtin_amdgcn_s_setprio(0);
    // boundary sync: A(t+1,0),B(t+1,0) landed; A(t+1,1),B(t+1,1) in flight
    if (pf) SYNC_VM4();
  }
}

__device__ __forceinline__ void zero_acc8(f32x4 (&acc)[8][4]) {
  f32x4 z = {0.f, 0.f, 0.f, 0.f};
  #pragma unroll
  for (int i = 0; i < 8; ++i)
    #pragma unroll
    for (int j = 0; j < 4; ++j) acc[i][j] = z;
}

// ---------------------------------------------------------------------------
// 256-tile GEMM writing activation in per-head transposed layout Xt[b,h,d,s].
// A: [8192][K] f16, W: [2048][K] f16. N fixed = 2048 (8 heads x 256).
// ---------------------------------------------------------------------------
__global__ __launch_bounds__(512, 2) void gemm256_t_kernel(
    const f16* __restrict__ A, const f16* __restrict__ W,
    f16* __restrict__ Xt, int K) {
  int row0 = blockIdx.y * 256, col0 = blockIdx.x * 256;
  f32x4 acc[8][4];
  zero_acc8(acc);
  mm_core256(A + (size_t)row0 * K, W + (size_t)col0 * K, K, acc);
  int tid = threadIdx.x, lane = tid & 63, wv = tid >> 6;
  int wrow = (wv >> 2) * 128, wcol = (wv & 3) * 64;
  int cn = lane & 15, rbase = (lane >> 4) * 4;
  int b = row0 >> 10, sbase = row0 & 1023;
  #pragma unroll
  for (int m = 0; m < 8; ++m) {
    int s = sbase + wrow + m * 16 + rbase;           // 4 consecutive s
    #pragma unroll
    for (int n = 0; n < 4; ++n) {
      int col = col0 + wcol + n * 16 + cn;
      int h = col >> 8, d = col & 255;
      f16x4 v = {(f16)acc[m][n][0], (f16)acc[m][n][1],
                 (f16)acc[m][n][2], (f16)acc[m][n][3]};
      *(f16x4*)&Xt[(((size_t)(b * 8 + h) * 256 + d) << 10) + s] = v;
    }
  }
}

// ---------------------------------------------------------------------------
// 256-tile per-head seq mix + bias + square:
// Y[(b,t),(h,d)] = ( sum_s Mt[h,t,s] * Xt[b,h,d,s] + bias[h,d] )^2 (f16 out)
// grid: (1, SEQ/256, B*H). N-tile covers the full 256-d head.
// ---------------------------------------------------------------------------
__global__ __launch_bounds__(512, 2) void mut256_kernel(
    const f16* __restrict__ Mt, const f16* __restrict__ Xt,
    const float* __restrict__ bias, f16* __restrict__ Y) {
  int b = blockIdx.z >> 3, h = blockIdx.z & 7;
  int t0 = blockIdx.y * 256;
  f32x4 acc[8][4];
  zero_acc8(acc);
  const f16* Ap = Mt + ((size_t)h << 20) + ((size_t)t0 << 10);
  const f16* Bp = Xt + (((size_t)(b * 8 + h)) << 18);
  mm_core256(Ap, Bp, SEQ, acc);
  int tid = threadIdx.x, lane = tid & 63, wv = tid >> 6;
  int wrow = (wv >> 2) * 128, wcol = (wv & 3) * 64;
  int cn = lane & 15, rbase = (lane >> 4) * 4;
  #pragma unroll
  for (int m = 0; m < 8; ++m) {
    int t = t0 + wrow + m * 16 + rbase;
    #pragma unroll
    for (int n = 0; n < 4; ++n) {
      int d = wcol + n * 16 + cn;
      float bb = bias[(h << 8) + d];
      size_t base = (((size_t)(b << 10) + t) << 11) + (h << 8) + d;
      #pragma unroll
      for (int r = 0; r < 4; ++r) {
        float v = acc[m][n][r] + bb;
        Y[base + (size_t)r * INTER] = (f16)(v * v);
      }
    }
  }
}

// ===========================================================================
// 128x128 core (verified): BK=32, global_load_lds staging, double buffer.
// Kept for gemm3 (N=512 -> 256-tile grid would underfill the GPU).
// ===========================================================================
__device__ __forceinline__ void mm_core(const f16* __restrict__ At,
                                        const f16* __restrict__ Bt,
                                        int K, f32x4 (&acc)[4][4]) {
  __shared__ __align__(16) f16 As[2 * 4096];
  __shared__ __align__(16) f16 Bs[2 * 4096];
  const int tid  = threadIdx.x;
  const int lane = tid & 63, wv = tid >> 6;
  const int wm = (wv >> 1) * 64, wn = (wv & 1) * 64;
  const int lrow  = lane & 15;
  const int kfrag = (lane >> 4) * 8;
  const int c0  = wv * 128 + lane;
  const int r0c = c0 >> 2, q0c = c0 & 3;
  const int c1  = c0 + 64;
  const int r1c = c1 >> 2, q1c = c1 & 3;
  const int ga0 = r0c * K + ((q0c ^ ((r0c >> 1) & 3)) << 3);
  const int ga1 = r1c * K + ((q1c ^ ((r1c >> 1) & 3)) << 3);
  f16* lA0 = &As[wv * 1024];
  f16* lA1 = &As[wv * 1024 + 512];
  f16* lB0 = &Bs[wv * 1024];
  f16* lB1 = &Bs[wv * 1024 + 512];
  int aoff[4], boff[4];
  #pragma unroll
  for (int t = 0; t < 4; ++t) {
    int ra = wm + t * 16 + lrow;
    aoff[t] = ra * 32 + (kfrag ^ (((ra >> 1) & 3) << 3));
    int rb = wn + t * 16 + lrow;
    boff[t] = rb * 32 + (kfrag ^ (((rb >> 1) & 3) << 3));
  }
  g2l16(At + ga0, lA0);
  g2l16(At + ga1, lA1);
  g2l16(Bt + ga0, lB0);
  g2l16(Bt + ga1, lB1);
  __syncthreads();
  int cur = 0;
  for (int k0 = 0; k0 < K; k0 += 32) {
    if (k0 + 32 < K) {
      const int nb = (cur ^ 1) * 4096;
      g2l16(At + (k0 + 32) + ga0, lA0 + nb);
      g2l16(At + (k0 + 32) + ga1, lA1 + nb);
      g2l16(Bt + (k0 + 32) + ga0, lB0 + nb);
      g2l16(Bt + (k0 + 32) + ga1, lB1 + nb);
    }
    const int cb = cur * 4096;
    f16x8 af[4], bf[4];
    #pragma unroll
    for (int t = 0; t < 4; ++t) {
      af[t] = *(const f16x8*)&As[cb + aoff[t]];
      bf[t] = *(const f16x8*)&Bs[cb + boff[t]];
    }
    #pragma unroll
    for (int i = 0; i < 4; ++i)
      #pragma unroll
      for (int j = 0; j < 4; ++j)
        acc[i][j] = __builtin_amdgcn_mfma_f32_16x16x32_f16(af[i], bf[j],
                                                           acc[i][j], 0, 0, 0);
    __syncthreads();
    cur ^= 1;
  }
}

__device__ __forceinline__ void zero_acc(f32x4 (&acc)[4][4]) {
  f32x4 z = {0.f, 0.f, 0.f, 0.f};
  #pragma unroll
  for (int i = 0; i < 4; ++i)
    #pragma unroll
    for (int j = 0; j < 4; ++j) acc[i][j] = z;
}

// ---------------------------------------------------------------------------
// final GEMM: out fp32 = A @ W^T + bias.  A: [8192][K] f16, W: [N][K] f16.
// ---------------------------------------------------------------------------
__global__ __launch_bounds__(256) void gemm_out_kernel(
    const f16* __restrict__ A, const f16* __restrict__ W,
    const float* __restrict__ bias, float* __restrict__ out, int K, int N) {
  int row0 = blockIdx.y * 128, col0 = blockIdx.x * 128;
  f32x4 acc[4][4];
  zero_acc(acc);
  mm_core(A + (size_t)row0 * K, W + (size_t)col0 * K, K, acc);
  int tid = threadIdx.x, lane = tid & 63, wv = tid >> 6;
  int wm = (wv >> 1) * 64, wn = (wv & 1) * 64;
  int cn = lane & 15, rbase = (lane >> 4) * 4;
  #pragma unroll
  for (int mt = 0; mt < 4; ++mt) {
    int r0 = row0 + wm + mt * 16 + rbase;
    #pragma unroll
    for (int nt = 0; nt < 4; ++nt) {
      int col = col0 + wn + nt * 16 + cn;
      float bb = bias[col];
      #pragma unroll
      for (int r = 0; r < 4; ++r)
        out[(size_t)(r0 + r) * N + col] = acc[mt][nt][r] + bb;
    }
  }
}

// ---------------------------------------------------------------------------
// embeddings + layernorm -> f16
// ---------------------------------------------------------------------------
__global__ __launch_bounds__(256) void embed_ln_kernel(
    const int* __restrict__ x, const float* __restrict__ wemb,
    const float* __restrict__ pemb, const float* __restrict__ temb,
    const float* __restrict__ lnw, const float* __restrict__ lnb,
    f16* __restrict__ out) {
  int row = blockIdx.x;
  int s = row & (SEQ - 1);
  int tok = x[row];
  const float* we = wemb + (size_t)tok * HID;
  const float* pe = pemb + (size_t)s * HID;
  int c = threadIdx.x;
  float e0 = we[c] + pe[c] + temb[c];
  float e1 = we[c + 256] + pe[c + 256] + temb[c + 256];
  float s1 = e0 + e1, s2 = e0 * e0 + e1 * e1;
  #pragma unroll
  for (int off = 32; off > 0; off >>= 1) {
    s1 += __shfl_down(s1, off, 64);
    s2 += __shfl_down(s2, off, 64);
  }
  __shared__ float r1[4], r2[4];
  int wid = threadIdx.x >> 6, lane = threadIdx.x & 63;
  if (lane == 0) { r1[wid] = s1; r2[wid] = s2; }
  __syncthreads();
  float S1 = r1[0] + r1[1] + r1[2] + r1[3];
  float S2 = r2[0] + r2[1] + r2[2] + r2[3];
  float m = S1 * (1.0f / HID);
  float v = S2 * (1.0f / HID) - m * m;
  float inv = rsqrtf(v + 1e-12f);
  f16* o = out + (size_t)row * HID;
  o[c]       = (f16)((e0 - m) * inv * lnw[c]       + lnb[c]);
  o[c + 256] = (f16)((e1 - m) * inv * lnw[c + 256] + lnb[c + 256]);
}

// ---------------------------------------------------------------------------
// f32 -> f16 cast (n % 4 == 0)
// ---------------------------------------------------------------------------
__global__ __launch_bounds__(256) void cast_f16_kernel(
    const float* __restrict__ in, f16* __restrict__ out, int n) {
  int i = (blockIdx.x * 256 + threadIdx.x) * 4;
  if (i < n) {
    float4 v = *(const float4*)(in + i);
    f16x4 o = {(f16)v.x, (f16)v.y, (f16)v.z, (f16)v.w};
    *(f16x4*)(out + i) = o;
  }
}

// ---------------------------------------------------------------------------
// per-head transpose+cast: Mt[h][t][s] = (f16) M[h][s][t]   (1024x1024 x 8)
// ---------------------------------------------------------------------------
__global__ __launch_bounds__(256) void mtrans_kernel(
    const float* __restrict__ M, f16* __restrict__ Mt) {
  __shared__ float T[32][33];
  int h = blockIdx.z;
  int s0 = blockIdx.y * 32, t0 = blockIdx.x * 32;
  int tx = threadIdx.x & 31, ty = threadIdx.x >> 5;   // ty 0..7
  const float* Mh = M + ((size_t)h << 20);
  #pragma unroll
  for (int i = 0; i < 32; i += 8)
    T[ty + i][tx] = Mh[((size_t)(s0 + ty + i) << 10) + t0 + tx];
  __syncthreads();
  f16* Mth = Mt + ((size_t)h << 20);
  #pragma unroll
  for (int i = 0; i < 32; i += 8)
    Mth[((size_t)(t0 + ty + i) << 10) + s0 + tx] = (f16)T[tx][ty + i];
}

// ---------------------------------------------------------------------------
extern "C" void kernel_launch(void* const* d_in, const int* in_sizes, int n_in,
                              void* d_out, int out_size, void* d_ws, size_t ws_size,
                              hipStream_t stream) {
  const int*   x        = (const int*)d_in[0];
  const float* wemb     = (const float*)d_in[1];
  const float* pemb     = (const float*)d_in[2];
  const float* temb     = (const float*)d_in[3];
  const float* lnw      = (const float*)d_in[4];
  const float* lnb      = (const float*)d_in[5];
  const float* init_d   = (const float*)d_in[6];
  const float* init_b   = (const float*)d_in[7];
  const float* init_M   = (const float*)d_in[8];
  const float* inter0_d = (const float*)d_in[9];
  const float* inter0_b = (const float*)d_in[10];
  const float* inter0_M = (const float*)d_in[11];
  const float* final_d  = (const float*)d_in[12];
  const float* final_b  = (const float*)d_in[13];
  float* out = (float*)d_out;

  // aliased f16 workspace regions (bytes):
  char* ws = (char*)d_ws;
  f16* R0 = (f16*)(ws);                 //  8.4MB: X0 (8192x512)  then W2f (2048x2048)
  f16* R1 = (f16*)(ws + 8388608);       //  2.1MB: W1f (2048x512) then W3f (512x2048)
  f16* R2 = (f16*)(ws + 10485760);      // 16.8MB: Mt1 then Mt2   (8x1024x1024)
  f16* R3 = (f16*)(ws + 27262976);      // 33.6MB: Xt1 then bufD  (8192x2048)
  f16* R4 = (f16*)(ws + 60817408);      // 33.6MB: bufB
  f16* R5 = (f16*)(ws + 94371840);      // 33.6MB: Xt2

  // 1. embeddings + LN -> X0 (f16)
  embed_ln_kernel<<<ROWS, 256, 0, stream>>>(x, wemb, pemb, temb, lnw, lnb, R0);
  // 2. W1 -> f16 ; Mt1
  cast_f16_kernel<<<(INTER * HID / 4 + 255) / 256, 256, 0, stream>>>(init_d, R1, INTER * HID);
  mtrans_kernel<<<dim3(32, 32, 8), 256, 0, stream>>>(init_M, R2);
  // 3. gemm1: Xt1 = X0 @ W1^T  (transposed-per-head epilogue)
  gemm256_t_kernel<<<dim3(INTER / 256, ROWS / 256), 512, 0, stream>>>(R0, R1, R3, HID);
  // 4. mut1 -> bufB
  mut256_kernel<<<dim3(1, SEQ / 256, BATCH * NHEAD), 512, 0, stream>>>(R2, R3, init_b, R4);
  // 5. W2 -> f16 (over X0) ; Mt2 (over Mt1)
  cast_f16_kernel<<<(INTER * INTER / 4 + 255) / 256, 256, 0, stream>>>(inter0_d, R0, INTER * INTER);
  mtrans_kernel<<<dim3(32, 32, 8), 256, 0, stream>>>(inter0_M, R2);
  // 6. gemm2: Xt2 = bufB @ W2^T
  gemm256_t_kernel<<<dim3(INTER / 256, ROWS / 256), 512, 0, stream>>>(R4, R0, R5, INTER);
  // 7. mut2 -> bufD (over Xt1)
  mut256_kernel<<<dim3(1, SEQ / 256, BATCH * NHEAD), 512, 0, stream>>>(R2, R5, inter0_b, R3);
  // 8. W3 -> f16 (over W1f)
  cast_f16_kernel<<<(HID * INTER / 4 + 255) / 256, 256, 0, stream>>>(final_d, R1, HID * INTER);
  // 9. gemm3: out = bufD @ W3^T + bias (fp32 out)
  gemm_out_kernel<<<dim3(HID / 128, ROWS / 128), 256, 0, stream>>>(R3, R1, final_b, out, INTER, HID);
}

// Round 5
// 415.802 us; speedup vs baseline: 1.1764x; 1.0188x over previous
//
#include <hip/hip_runtime.h>

typedef _Float16 f16;
typedef _Float16 f16x4 __attribute__((ext_vector_type(4)));
typedef _Float16 f16x8 __attribute__((ext_vector_type(8)));
typedef float    f32x4 __attribute__((ext_vector_type(4)));

#define SEQ   1024
#define HID   512
#define NHEAD 8
#define DH    256
#define INTER 2048
#define BATCH 8
#define ROWS  (BATCH * SEQ)   // 8192

// async global->LDS, 16B per lane. LDS dest is wave-uniform base + lane*16.
__device__ __forceinline__ void g2l16(const void* g, void* l) {
  __builtin_amdgcn_global_load_lds(
      (const __attribute__((address_space(1))) void*)g,
      (__attribute__((address_space(3))) void*)l, 16, 0, 0);
}

// ===========================================================================
// 256x256 core, 4-slot LDS ring, ONE mid-iteration barrier per K-32 subtile.
// C(256x256) += A(256xK) * B^T(256xK); operands k-fast row-major, ld == K.
// 512 threads = 8 waves (2M x 4N); per-wave output 128x64 = acc[8][4].
// LDS: 4 ring slots x (A 16KiB + B 16KiB) = 128 KiB.
// Iter t: reads0(slot t) ; MFMA0 ; reads1(slot t) ; stage tile t+3 into
// slot (t+3)&3 ; vmcnt(8)+s_barrier ; MFMA1.  Post-barrier MFMA1 is
// independent of iter t+1's reads -> compiler schedules next reads under it
// (the overlap r3/r4 lacked).  Safety is barrier-ordered: slot t is only
// read BEFORE barrier(t) and only overwritten by staging of t+4, which is
// issued AFTER barrier(t).  vmcnt(8) = tiles t+2,t+3 (8 calls) in flight,
// tile t+1 guaranteed landed; tail: vmcnt(4) -> vmcnt(0) -> skip.
// Swizzle (verified, 0-conflict): k-octet q of row r at slot q^((r>>1)&3),
// involution pre-applied on the GLOBAL source address; ds_read matches.
// ===========================================================================
__device__ __forceinline__ void mm_core256(const f16* __restrict__ At,
                                           const f16* __restrict__ Bt,
                                           int K, f32x4 (&acc)[8][4]) {
  __shared__ __align__(16) f16 As[4 * 8192];
  __shared__ __align__(16) f16 Bs[4 * 8192];
  const int tid  = threadIdx.x;
  const int lane = tid & 63, wv = tid >> 6;
  const int wrow = (wv >> 2) * 128, wcol = (wv & 3) * 64;

  // staging: subtile = 256 rows x 4 k-octets = 1024 chunks of 16B; 2 calls.
  // call j covers chunk j*512+tid: r=c>>2, s=c&3, global octet q=s^((r>>1)&3).
  const int c0 = tid, c1 = tid + 512;
  const int r0 = c0 >> 2, s0 = c0 & 3;
  const int r1 = c1 >> 2, s1 = c1 & 3;
  const int g0 = r0 * K + ((s0 ^ ((r0 >> 1) & 3)) << 3);  // pre-swizzled src
  const int g1 = r1 * K + ((s1 ^ ((r1 >> 1) & 3)) << 3);
  const int l0 = wv * 512;          // per-wave LDS base (f16), call 0
  const int l1 = 4096 + wv * 512;   // call 1

  // fragment read offsets within a subtile (swizzled, matches source perm)
  int aoff[8], boff[4];
  const int q = lane >> 4;
  #pragma unroll
  for (int m = 0; m < 8; ++m) {
    int r = wrow + m * 16 + (lane & 15);
    aoff[m] = r * 32 + ((q ^ ((r >> 1) & 3)) << 3);
  }
  #pragma unroll
  for (int n = 0; n < 4; ++n) {
    int r = wcol + n * 16 + (lane & 15);
    boff[n] = r * 32 + ((q ^ ((r >> 1) & 3)) << 3);
  }

  const int nt = K >> 5;   // K-32 subtiles
  // prologue: stage tiles 0,1,2 -> slots 0,1,2 (12 calls, 4 per tile)
  #pragma unroll
  for (int p = 0; p < 3; ++p) {
    const int kb = p << 5, sb = p * 8192;
    g2l16(At + kb + g0, &As[sb + l0]);
    g2l16(At + kb + g1, &As[sb + l1]);
    g2l16(Bt + kb + g0, &Bs[sb + l0]);
    g2l16(Bt + kb + g1, &Bs[sb + l1]);
  }
  asm volatile("s_waitcnt vmcnt(8)" ::: "memory");   // tile 0 landed
  __builtin_amdgcn_s_barrier();

  for (int t = 0; t < nt; ++t) {
    const int cb = (t & 3) * 8192;

    // reads0: B-frags + A-frags (lower half) from slot t
    f16x8 bfr[4], af0[4], af1[4];
    #pragma unroll
    for (int n = 0; n < 4; ++n) bfr[n] = *(const f16x8*)&Bs[cb + boff[n]];
    #pragma unroll
    for (int m = 0; m < 4; ++m) af0[m] = *(const f16x8*)&As[cb + aoff[m]];

    // MFMA cluster 0
    __builtin_amdgcn_s_setprio(1);
    #pragma unroll
    for (int m = 0; m < 4; ++m)
      #pragma unroll
      for (int n = 0; n < 4; ++n)
        acc[m][n] = __builtin_amdgcn_mfma_f32_16x16x32_f16(af0[m], bfr[n],
                                                           acc[m][n], 0, 0, 0);
    __builtin_amdgcn_s_setprio(0);

    // reads1: A-frags (upper half) from slot t — still pre-barrier
    #pragma unroll
    for (int m = 0; m < 4; ++m) af1[m] = *(const f16x8*)&As[cb + aoff[m + 4]];

    // stage tile t+3 into slot (t+3)&3 (disjoint from slots t..t+2)
    if (t + 3 < nt) {
      const int kb = (t + 3) << 5, sb = ((t + 3) & 3) * 8192;
      g2l16(At + kb + g0, &As[sb + l0]);
      g2l16(At + kb + g1, &As[sb + l1]);
      g2l16(Bt + kb + g0, &Bs[sb + l0]);
      g2l16(Bt + kb + g1, &Bs[sb + l1]);
    }

    // single per-subtile sync: tile t+1 guaranteed resident after this
    if (t + 1 < nt) {
      if (t + 3 < nt)      asm volatile("s_waitcnt vmcnt(8)" ::: "memory");
      else if (t + 2 < nt) asm volatile("s_waitcnt vmcnt(4)" ::: "memory");
      else                 asm volatile("s_waitcnt vmcnt(0)" ::: "memory");
      __builtin_amdgcn_s_barrier();
    }

    // MFMA cluster 1 — post-barrier; next iter's reads overlap this
    __builtin_amdgcn_s_setprio(1);
    #pragma unroll
    for (int m = 0; m < 4; ++m)
      #pragma unroll
      for (int n = 0; n < 4; ++n)
        acc[m + 4][n] = __builtin_amdgcn_mfma_f32_16x16x32_f16(af1[m], bfr[n],
                                                               acc[m + 4][n], 0, 0, 0);
    __builtin_amdgcn_s_setprio(0);
  }
}

__device__ __forceinline__ void zero_acc8(f32x4 (&acc)[8][4]) {
  f32x4 z = {0.f, 0.f, 0.f, 0.f};
  #pragma unroll
  for (int i = 0; i < 8; ++i)
    #pragma unroll
    for (int j = 0; j < 4; ++j) acc[i][j] = z;
}

// ---------------------------------------------------------------------------
// 256-tile GEMM writing activation in per-head transposed layout Xt[b,h,d,s].
// A: [8192][K] f16, W: [2048][K] f16. N fixed = 2048 (8 heads x 256).
// ---------------------------------------------------------------------------
__global__ __launch_bounds__(512, 2) void gemm256_t_kernel(
    const f16* __restrict__ A, const f16* __restrict__ W,
    f16* __restrict__ Xt, int K) {
  int row0 = blockIdx.y * 256, col0 = blockIdx.x * 256;
  f32x4 acc[8][4];
  zero_acc8(acc);
  mm_core256(A + (size_t)row0 * K, W + (size_t)col0 * K, K, acc);
  int tid = threadIdx.x, lane = tid & 63, wv = tid >> 6;
  int wrow = (wv >> 2) * 128, wcol = (wv & 3) * 64;
  int cn = lane & 15, rbase = (lane >> 4) * 4;
  int b = row0 >> 10, sbase = row0 & 1023;
  #pragma unroll
  for (int m = 0; m < 8; ++m) {
    int s = sbase + wrow + m * 16 + rbase;           // 4 consecutive s
    #pragma unroll
    for (int n = 0; n < 4; ++n) {
      int col = col0 + wcol + n * 16 + cn;
      int h = col >> 8, d = col & 255;
      f16x4 v = {(f16)acc[m][n][0], (f16)acc[m][n][1],
                 (f16)acc[m][n][2], (f16)acc[m][n][3]};
      *(f16x4*)&Xt[(((size_t)(b * 8 + h) * 256 + d) << 10) + s] = v;
    }
  }
}

// ---------------------------------------------------------------------------
// 256-tile per-head seq mix + bias + square:
// Y[(b,t),(h,d)] = ( sum_s Mt[h,t,s] * Xt[b,h,d,s] + bias[h,d] )^2 (f16 out)
// grid: (1, SEQ/256, B*H). N-tile covers the full 256-d head.
// ---------------------------------------------------------------------------
__global__ __launch_bounds__(512, 2) void mut256_kernel(
    const f16* __restrict__ Mt, const f16* __restrict__ Xt,
    const float* __restrict__ bias, f16* __restrict__ Y) {
  int b = blockIdx.z >> 3, h = blockIdx.z & 7;
  int t0 = blockIdx.y * 256;
  f32x4 acc[8][4];
  zero_acc8(acc);
  const f16* Ap = Mt + ((size_t)h << 20) + ((size_t)t0 << 10);
  const f16* Bp = Xt + (((size_t)(b * 8 + h)) << 18);
  mm_core256(Ap, Bp, SEQ, acc);
  int tid = threadIdx.x, lane = tid & 63, wv = tid >> 6;
  int wrow = (wv >> 2) * 128, wcol = (wv & 3) * 64;
  int cn = lane & 15, rbase = (lane >> 4) * 4;
  #pragma unroll
  for (int m = 0; m < 8; ++m) {
    int t = t0 + wrow + m * 16 + rbase;
    #pragma unroll
    for (int n = 0; n < 4; ++n) {
      int d = wcol + n * 16 + cn;
      float bb = bias[(h << 8) + d];
      size_t base = (((size_t)(b << 10) + t) << 11) + (h << 8) + d;
      #pragma unroll
      for (int r = 0; r < 4; ++r) {
        float v = acc[m][n][r] + bb;
        Y[base + (size_t)r * INTER] = (f16)(v * v);
      }
    }
  }
}

// ===========================================================================
// 128x128 core (verified): BK=32, global_load_lds staging, double buffer.
// Kept for gemm3 (N=512 -> 256-tile grid would underfill the GPU).
// ===========================================================================
__device__ __forceinline__ void mm_core(const f16* __restrict__ At,
                                        const f16* __restrict__ Bt,
                                        int K, f32x4 (&acc)[4][4]) {
  __shared__ __align__(16) f16 As[2 * 4096];
  __shared__ __align__(16) f16 Bs[2 * 4096];
  const int tid  = threadIdx.x;
  const int lane = tid & 63, wv = tid >> 6;
  const int wm = (wv >> 1) * 64, wn = (wv & 1) * 64;
  const int lrow  = lane & 15;
  const int kfrag = (lane >> 4) * 8;
  const int c0  = wv * 128 + lane;
  const int r0c = c0 >> 2, q0c = c0 & 3;
  const int c1  = c0 + 64;
  const int r1c = c1 >> 2, q1c = c1 & 3;
  const int ga0 = r0c * K + ((q0c ^ ((r0c >> 1) & 3)) << 3);
  const int ga1 = r1c * K + ((q1c ^ ((r1c >> 1) & 3)) << 3);
  f16* lA0 = &As[wv * 1024];
  f16* lA1 = &As[wv * 1024 + 512];
  f16* lB0 = &Bs[wv * 1024];
  f16* lB1 = &Bs[wv * 1024 + 512];
  int aoff[4], boff[4];
  #pragma unroll
  for (int t = 0; t < 4; ++t) {
    int ra = wm + t * 16 + lrow;
    aoff[t] = ra * 32 + (kfrag ^ (((ra >> 1) & 3) << 3));
    int rb = wn + t * 16 + lrow;
    boff[t] = rb * 32 + (kfrag ^ (((rb >> 1) & 3) << 3));
  }
  g2l16(At + ga0, lA0);
  g2l16(At + ga1, lA1);
  g2l16(Bt + ga0, lB0);
  g2l16(Bt + ga1, lB1);
  __syncthreads();
  int cur = 0;
  for (int k0 = 0; k0 < K; k0 += 32) {
    if (k0 + 32 < K) {
      const int nb = (cur ^ 1) * 4096;
      g2l16(At + (k0 + 32) + ga0, lA0 + nb);
      g2l16(At + (k0 + 32) + ga1, lA1 + nb);
      g2l16(Bt + (k0 + 32) + ga0, lB0 + nb);
      g2l16(Bt + (k0 + 32) + ga1, lB1 + nb);
    }
    const int cb = cur * 4096;
    f16x8 af[4], bf[4];
    #pragma unroll
    for (int t = 0; t < 4; ++t) {
      af[t] = *(const f16x8*)&As[cb + aoff[t]];
      bf[t] = *(const f16x8*)&Bs[cb + boff[t]];
    }
    #pragma unroll
    for (int i = 0; i < 4; ++i)
      #pragma unroll
      for (int j = 0; j < 4; ++j)
        acc[i][j] = __builtin_amdgcn_mfma_f32_16x16x32_f16(af[i], bf[j],
                                                           acc[i][j], 0, 0, 0);
    __syncthreads();
    cur ^= 1;
  }
}

__device__ __forceinline__ void zero_acc(f32x4 (&acc)[4][4]) {
  f32x4 z = {0.f, 0.f, 0.f, 0.f};
  #pragma unroll
  for (int i = 0; i < 4; ++i)
    #pragma unroll
    for (int j = 0; j < 4; ++j) acc[i][j] = z;
}

// ---------------------------------------------------------------------------
// final GEMM: out fp32 = A @ W^T + bias.  A: [8192][K] f16, W: [N][K] f16.
// ---------------------------------------------------------------------------
__global__ __launch_bounds__(256) void gemm_out_kernel(
    const f16* __restrict__ A, const f16* __restrict__ W,
    const float* __restrict__ bias, float* __restrict__ out, int K, int N) {
  int row0 = blockIdx.y * 128, col0 = blockIdx.x * 128;
  f32x4 acc[4][4];
  zero_acc(acc);
  mm_core(A + (size_t)row0 * K, W + (size_t)col0 * K, K, acc);
  int tid = threadIdx.x, lane = tid & 63, wv = tid >> 6;
  int wm = (wv >> 1) * 64, wn = (wv & 1) * 64;
  int cn = lane & 15, rbase = (lane >> 4) * 4;
  #pragma unroll
  for (int mt = 0; mt < 4; ++mt) {
    int r0 = row0 + wm + mt * 16 + rbase;
    #pragma unroll
    for (int nt = 0; nt < 4; ++nt) {
      int col = col0 + wn + nt * 16 + cn;
      float bb = bias[col];
      #pragma unroll
      for (int r = 0; r < 4; ++r)
        out[(size_t)(r0 + r) * N + col] = acc[mt][nt][r] + bb;
    }
  }
}

// ---------------------------------------------------------------------------
// embeddings + layernorm -> f16
// ---------------------------------------------------------------------------
__global__ __launch_bounds__(256) void embed_ln_kernel(
    const int* __restrict__ x, const float* __restrict__ wemb,
    const float* __restrict__ pemb, const float* __restrict__ temb,
    const float* __restrict__ lnw, const float* __restrict__ lnb,
    f16* __restrict__ out) {
  int row = blockIdx.x;
  int s = row & (SEQ - 1);
  int tok = x[row];
  const float* we = wemb + (size_t)tok * HID;
  const float* pe = pemb + (size_t)s * HID;
  int c = threadIdx.x;
  float e0 = we[c] + pe[c] + temb[c];
  float e1 = we[c + 256] + pe[c + 256] + temb[c + 256];
  float s1 = e0 + e1, s2 = e0 * e0 + e1 * e1;
  #pragma unroll
  for (int off = 32; off > 0; off >>= 1) {
    s1 += __shfl_down(s1, off, 64);
    s2 += __shfl_down(s2, off, 64);
  }
  __shared__ float r1[4], r2[4];
  int wid = threadIdx.x >> 6, lane = threadIdx.x & 63;
  if (lane == 0) { r1[wid] = s1; r2[wid] = s2; }
  __syncthreads();
  float S1 = r1[0] + r1[1] + r1[2] + r1[3];
  float S2 = r2[0] + r2[1] + r2[2] + r2[3];
  float m = S1 * (1.0f / HID);
  float v = S2 * (1.0f / HID) - m * m;
  float inv = rsqrtf(v + 1e-12f);
  f16* o = out + (size_t)row * HID;
  o[c]       = (f16)((e0 - m) * inv * lnw[c]       + lnb[c]);
  o[c + 256] = (f16)((e1 - m) * inv * lnw[c + 256] + lnb[c + 256]);
}

// ---------------------------------------------------------------------------
// f32 -> f16 cast (n % 4 == 0)
// ---------------------------------------------------------------------------
__global__ __launch_bounds__(256) void cast_f16_kernel(
    const float* __restrict__ in, f16* __restrict__ out, int n) {
  int i = (blockIdx.x * 256 + threadIdx.x) * 4;
  if (i < n) {
    float4 v = *(const float4*)(in + i);
    f16x4 o = {(f16)v.x, (f16)v.y, (f16)v.z, (f16)v.w};
    *(f16x4*)(out + i) = o;
  }
}

// ---------------------------------------------------------------------------
// per-head transpose+cast: Mt[h][t][s] = (f16) M[h][s][t]   (1024x1024 x 8)
// ---------------------------------------------------------------------------
__global__ __launch_bounds__(256) void mtrans_kernel(
    const float* __restrict__ M, f16* __restrict__ Mt) {
  __shared__ float T[32][33];
  int h = blockIdx.z;
  int s0 = blockIdx.y * 32, t0 = blockIdx.x * 32;
  int tx = threadIdx.x & 31, ty = threadIdx.x >> 5;   // ty 0..7
  const float* Mh = M + ((size_t)h << 20);
  #pragma unroll
  for (int i = 0; i < 32; i += 8)
    T[ty + i][tx] = Mh[((size_t)(s0 + ty + i) << 10) + t0 + tx];
  __syncthreads();
  f16* Mth = Mt + ((size_t)h << 20);
  #pragma unroll
  for (int i = 0; i < 32; i += 8)
    Mth[((size_t)(t0 + ty + i) << 10) + s0 + tx] = (f16)T[tx][ty + i];
}

// ---------------------------------------------------------------------------
extern "C" void kernel_launch(void* const* d_in, const int* in_sizes, int n_in,
                              void* d_out, int out_size, void* d_ws, size_t ws_size,
                              hipStream_t stream) {
  const int*   x        = (const int*)d_in[0];
  const float* wemb     = (const float*)d_in[1];
  const float* pemb     = (const float*)d_in[2];
  const float* temb     = (const float*)d_in[3];
  const float* lnw      = (const float*)d_in[4];
  const float* lnb      = (const float*)d_in[5];
  const float* init_d   = (const float*)d_in[6];
  const float* init_b   = (const float*)d_in[7];
  const float* init_M   = (const float*)d_in[8];
  const float* inter0_d = (const float*)d_in[9];
  const float* inter0_b = (const float*)d_in[10];
  const float* inter0_M = (const float*)d_in[11];
  const float* final_d  = (const float*)d_in[12];
  const float* final_b  = (const float*)d_in[13];
  float* out = (float*)d_out;

  // aliased f16 workspace regions (bytes):
  char* ws = (char*)d_ws;
  f16* R0 = (f16*)(ws);                 //  8.4MB: X0 (8192x512)  then W2f (2048x2048)
  f16* R1 = (f16*)(ws + 8388608);       //  2.1MB: W1f (2048x512) then W3f (512x2048)
  f16* R2 = (f16*)(ws + 10485760);      // 16.8MB: Mt1 then Mt2   (8x1024x1024)
  f16* R3 = (f16*)(ws + 27262976);      // 33.6MB: Xt1 then bufD  (8192x2048)
  f16* R4 = (f16*)(ws + 60817408);      // 33.6MB: bufB
  f16* R5 = (f16*)(ws + 94371840);      // 33.6MB: Xt2

  // 1. embeddings + LN -> X0 (f16)
  embed_ln_kernel<<<ROWS, 256, 0, stream>>>(x, wemb, pemb, temb, lnw, lnb, R0);
  // 2. W1 -> f16 ; Mt1
  cast_f16_kernel<<<(INTER * HID / 4 + 255) / 256, 256, 0, stream>>>(init_d, R1, INTER * HID);
  mtrans_kernel<<<dim3(32, 32, 8), 256, 0, stream>>>(init_M, R2);
  // 3. gemm1: Xt1 = X0 @ W1^T  (transposed-per-head epilogue)
  gemm256_t_kernel<<<dim3(INTER / 256, ROWS / 256), 512, 0, stream>>>(R0, R1, R3, HID);
  // 4. mut1 -> bufB
  mut256_kernel<<<dim3(1, SEQ / 256, BATCH * NHEAD), 512, 0, stream>>>(R2, R3, init_b, R4);
  // 5. W2 -> f16 (over X0) ; Mt2 (over Mt1)
  cast_f16_kernel<<<(INTER * INTER / 4 + 255) / 256, 256, 0, stream>>>(inter0_d, R0, INTER * INTER);
  mtrans_kernel<<<dim3(32, 32, 8), 256, 0, stream>>>(inter0_M, R2);
  // 6. gemm2: Xt2 = bufB @ W2^T
  gemm256_t_kernel<<<dim3(INTER / 256, ROWS / 256), 512, 0, stream>>>(R4, R0, R5, INTER);
  // 7. mut2 -> bufD (over Xt1)
  mut256_kernel<<<dim3(1, SEQ / 256, BATCH * NHEAD), 512, 0, stream>>>(R2, R5, inter0_b, R3);
  // 8. W3 -> f16 (over W1f)
  cast_f16_kernel<<<(HID * INTER / 4 + 255) / 256, 256, 0, stream>>>(final_d, R1, HID * INTER);
  // 9. gemm3: out = bufD @ W3^T + bias (fp32 out)
  gemm_out_kernel<<<dim3(HID / 128, ROWS / 128), 256, 0, stream>>>(R3, R1, final_b, out, INTER, HID);
}